// Round 4
// baseline (361.330 us; speedup 1.0000x reference)
//
#include <hip/hip_runtime.h>
#include <hip/hip_bf16.h>

// Problem constants (from reference)
#define BATCH 2
#define SEQ   2048
#define DMODEL 1024
#define NHEAD 16
#define DK    64
#define MTOK  (BATCH * SEQ)      // 4096 rows for the projection GEMMs

typedef __attribute__((ext_vector_type(8))) short bf16x8;   // 8 bf16 in 4 VGPRs
typedef __attribute__((ext_vector_type(4))) float f32x4;    // MFMA 16x16 accumulator

// float -> bf16 bits, round-to-nearest-even
__device__ __forceinline__ unsigned short f2bf(float x) {
    unsigned u = __float_as_uint(x);
    u = (u + 0x7FFFu + ((u >> 16) & 1u)) >> 16;
    return (unsigned short)u;
}

__device__ __forceinline__ void store_out(float* p, float v)          { *p = v; }
__device__ __forceinline__ void store_out(unsigned short* p, float v) { *p = f2bf(v); }

// async global->LDS, 16 B per lane; LDS dest = wave-uniform base + lane*16.
// Per-lane SOURCE addresses are arbitrary (gather) — verified in round-2/3 GEMM.
__device__ __forceinline__ void g2lds16(const void* g, void* l) {
    __builtin_amdgcn_global_load_lds(
        (const __attribute__((address_space(1))) void*)g,
        (__attribute__((address_space(3))) void*)l, 16, 0, 0);
}

// ---------------------------------------------------------------------------
// fp32 -> bf16 elementwise convert, 3 tensors in one launch (z selects).
// ---------------------------------------------------------------------------
__global__ __launch_bounds__(256) void cvt3_bf16_kernel(
    const float* __restrict__ s0, const float* __restrict__ s1,
    const float* __restrict__ s2,
    unsigned short* __restrict__ d0, unsigned short* __restrict__ d1,
    unsigned short* __restrict__ d2, int n)
{
    const float* src; unsigned short* dst;
    switch (blockIdx.z) {
        case 0:  src = s0; dst = d0; break;
        case 1:  src = s1; dst = d1; break;
        default: src = s2; dst = d2; break;
    }
    int i = (blockIdx.x * 256 + threadIdx.x) * 8;
    if (i >= n) return;
    float4 a = *(const float4*)(src + i);
    float4 b = *(const float4*)(src + i + 4);
    union { unsigned short s[8]; uint4 u; } o;
    o.s[0] = f2bf(a.x); o.s[1] = f2bf(a.y); o.s[2] = f2bf(a.z); o.s[3] = f2bf(a.w);
    o.s[4] = f2bf(b.x); o.s[5] = f2bf(b.y); o.s[6] = f2bf(b.z); o.s[7] = f2bf(b.w);
    *(uint4*)(dst + i) = o.u;
}

// ---------------------------------------------------------------------------
// Transpose + convert the 4 weight matrices: Wt[n][k] = (bf16)W[k][n], 1024^2.
// ---------------------------------------------------------------------------
__global__ __launch_bounds__(256) void wtrans_kernel(
    const float* __restrict__ w0, const float* __restrict__ w1,
    const float* __restrict__ w2, const float* __restrict__ w3,
    unsigned short* __restrict__ t0, unsigned short* __restrict__ t1,
    unsigned short* __restrict__ t2, unsigned short* __restrict__ t3)
{
    __shared__ float tile[32][33];
    const float* W; unsigned short* T;
    switch (blockIdx.z) {
        case 0:  W = w0; T = t0; break;
        case 1:  W = w1; T = t1; break;
        case 2:  W = w2; T = t2; break;
        default: W = w3; T = t3; break;
    }
    const int n0 = blockIdx.x * 32, k0 = blockIdx.y * 32;
    const int t  = threadIdx.x;
    const int r  = t >> 3;          // 0..31
    const int c4 = (t & 7) * 4;     // 0..28

    float4 v = *(const float4*)&W[(size_t)(k0 + r) * DMODEL + n0 + c4];
    tile[r][c4 + 0] = v.x; tile[r][c4 + 1] = v.y;
    tile[r][c4 + 2] = v.z; tile[r][c4 + 3] = v.w;
    __syncthreads();

    union { unsigned short s[4]; uint2 u; } o;
#pragma unroll
    for (int u = 0; u < 4; ++u) o.s[u] = f2bf(tile[c4 + u][r]);
    *(uint2*)&T[(size_t)(n0 + r) * DMODEL + k0 + c4] = o.u;
}

// ---------------------------------------------------------------------------
// LDS-free MFMA GEMM: C[M,N] = A[M,K] @ Bt[N,K]^T + bias (fp32 acc).
// A/B fragments are per-lane-contiguous 16 B -> load straight to VGPR.
// No LDS, NO BARRIERS: explicit ping-pong prefetch lets the compiler emit the
// AITER-style MFMA <-> buffer_load interleave with fine-grained vmcnt(N).
// Tile 128 x (NT*32). 4 waves: wm=w>>1 row-half, wn=w&1 col-half.
// z-fused: blockIdx.z selects one of up to 3 independent GEMMs.
// ---------------------------------------------------------------------------
struct Gemm3 {
    const unsigned short* A[3];
    const unsigned short* Bt[3];
    const float* bias[3];
    void* C[3];
};

template <typename OutT, int NT>
__global__ __launch_bounds__(256) void gemm_direct_kernel(Gemm3 g, int M, int N, int K)
{
    const int z = blockIdx.z;
    const unsigned short* __restrict__ A  = g.A[z];
    const unsigned short* __restrict__ Bt = g.Bt[z];
    const float* __restrict__ bias = g.bias[z];
    OutT* __restrict__ C = (OutT*)g.C[z];

    const int t    = threadIdx.x;
    const int w    = t >> 6;
    const int lane = t & 63;
    const int ln   = lane & 15;
    const int qg   = lane >> 4;
    const int wm   = w >> 1;
    const int wn   = w & 1;
    const int row0 = blockIdx.y * 128;
    const int col0 = blockIdx.x * (NT * 32);

    const unsigned short* ap[4];
    const unsigned short* bp[NT];
#pragma unroll
    for (int mt = 0; mt < 4; ++mt)
        ap[mt] = A + (size_t)(row0 + wm * 64 + mt * 16 + ln) * K + qg * 8;
#pragma unroll
    for (int nt = 0; nt < NT; ++nt)
        bp[nt] = Bt + (size_t)(col0 + wn * NT * 16 + nt * 16 + ln) * K + qg * 8;

    f32x4 acc[4][NT];
#pragma unroll
    for (int mt = 0; mt < 4; ++mt)
#pragma unroll
        for (int nt = 0; nt < NT; ++nt) acc[mt][nt] = (f32x4){0.f, 0.f, 0.f, 0.f};

    bf16x8 aX[4], bX[NT], aY[4], bY[NT];

#define LOADF(dstA, dstB, ks_)                                                 \
    {                                                                          \
        const int off = (ks_) * 32;                                            \
        _Pragma("unroll")                                                      \
        for (int mt = 0; mt < 4; ++mt) dstA[mt] = *(const bf16x8*)(ap[mt] + off); \
        _Pragma("unroll")                                                      \
        for (int nt = 0; nt < NT; ++nt) dstB[nt] = *(const bf16x8*)(bp[nt] + off); \
    }
#define MFMAF(srcA, srcB)                                                      \
    {                                                                          \
        _Pragma("unroll")                                                      \
        for (int mt = 0; mt < 4; ++mt)                                         \
            _Pragma("unroll")                                                  \
            for (int nt = 0; nt < NT; ++nt)                                    \
                acc[mt][nt] = __builtin_amdgcn_mfma_f32_16x16x32_bf16(         \
                    srcA[mt], srcB[nt], acc[mt][nt], 0, 0, 0);                 \
    }

    const int KS = K / 32;          // 32 steps
    LOADF(aX, bX, 0)
    for (int ks = 0; ks < KS - 2; ks += 2) {
        LOADF(aY, bY, ks + 1)
        MFMAF(aX, bX)
        LOADF(aX, bX, ks + 2)
        MFMAF(aY, bY)
    }
    LOADF(aY, bY, KS - 1)
    MFMAF(aX, bX)
    MFMAF(aY, bY)
#undef LOADF
#undef MFMAF

    float bfv[NT];
#pragma unroll
    for (int nt = 0; nt < NT; ++nt)
        bfv[nt] = bias[col0 + wn * NT * 16 + nt * 16 + ln];

#pragma unroll
    for (int mt = 0; mt < 4; ++mt)
#pragma unroll
        for (int nt = 0; nt < NT; ++nt)
#pragma unroll
            for (int r = 0; r < 4; ++r) {
                int row = row0 + wm * 64 + mt * 16 + qg * 4 + r;
                int col = col0 + wn * NT * 16 + nt * 16 + ln;
                store_out(&C[(size_t)row * N + col], acc[mt][nt][r] + bfv[nt]);
            }
}

// ---------------------------------------------------------------------------
// Flash attention with MFMA. Staging overhaul vs round 3:
//  - Q, K: fragment-ordered global_load_lds gather (conflict-free, no VALU)
//  - V: in-LDS transpose with XOR swizzle addr = dk*64 + (j ^ 8*((dk>>3)&7))
//        -> writes hit all 32 banks (2-way, free), b128 reads stay aligned
//  - sP: row-major stride 72 with col ^ 8*((row>>2)&7) swizzle (2-way writes)
// ---------------------------------------------------------------------------
#define BR 64
#define BC 64
#define PSTR 72

__global__ __launch_bounds__(256, 4) void attn_mfma_kernel(
    const unsigned short* __restrict__ Qg, const unsigned short* __restrict__ Kg,
    const unsigned short* __restrict__ Vg, unsigned short* __restrict__ O)
{
    __shared__ unsigned short sQ[8 * 512];      // 8 frag-blocks of 1 KB
    __shared__ unsigned short sK[8 * 512];
    __shared__ unsigned short sVt[DK * 64];     // swizzled [dk][j]
    __shared__ unsigned short sP[BR * PSTR];

    const int t    = threadIdx.x;
    const int w    = t >> 6;
    const int lane = t & 63;
    const int ln   = lane & 15;
    const int qg   = lane >> 4;

    const int id  = blockIdx.x;
    const int bh  = id & 31;
    const int qt  = (SEQ / BR - 1) - (id >> 5);   // heavy tiles first
    const int b   = bh >> 4;
    const int h   = bh & 15;
    const int qi0 = qt * BR;

    const size_t rowbase = (size_t)b * SEQ;
    const size_t colbase = (size_t)h * DK;

    // ---- stage Q tile via gather: block s=(ws,kc); wave w stages s=w*2+i ----
#pragma unroll
    for (int i = 0; i < 2; ++i) {
        const int s = w * 2 + i;                 // ws = w, kc = i
        const unsigned short* gp =
            Qg + (rowbase + qi0 + w * 16 + ln) * DMODEL + colbase + i * 32 + qg * 8;
        g2lds16(gp, &sQ[s * 512]);
    }
    __syncthreads();

    bf16x8 aq[2];
#pragma unroll
    for (int kc = 0; kc < 2; ++kc)
        aq[kc] = *(const bf16x8*)&sQ[(w * 2 + kc) * 512 + lane * 8];

    f32x4 ofrag[4];
#pragma unroll
    for (int nt = 0; nt < 4; ++nt) ofrag[nt] = (f32x4){0.f, 0.f, 0.f, 0.f};
    float m_r[4], l_r[4];
#pragma unroll
    for (int r = 0; r < 4; ++r) { m_r[r] = -3.0e38f; l_r[r] = 0.f; }

    for (int j0 = 0; j0 <= qi0; j0 += BC) {
        __syncthreads();                         // prev tile's LDS reads done

        // ---- K tile: 8 gather blocks (nt,kc), wave w stages s=w*2+i ----
#pragma unroll
        for (int i = 0; i < 2; ++i) {
            const int s  = w * 2 + i;
            const int nt = s >> 1, kc = s & 1;
            const unsigned short* gp =
                Kg + (rowbase + j0 + nt * 16 + ln) * DMODEL + colbase + kc * 32 + qg * 8;
            g2lds16(gp, &sK[s * 512]);
        }
        // ---- V tile: swizzled transpose sVt[dk*64 + (j ^ 8*ci)], ci=(dk>>3)&7 ----
#pragma unroll
        for (int it = 0; it < 2; ++it) {
            int chunk = t + 256 * it;            // 0..511
            int r  = chunk >> 3;                 // j row 0..63
            int c  = (chunk & 7) * 8;            // dk base
            int ci = chunk & 7;                  // = (c+u)>>3 for u<8
            union { uint4 u; unsigned short s[8]; } d;
            d.u = *(const uint4*)&Vg[(rowbase + j0 + r) * DMODEL + colbase + c];
#pragma unroll
            for (int u = 0; u < 8; ++u)
                sVt[(c + u) * 64 + (r ^ (ci * 8))] = d.s[u];
        }
        __syncthreads();                         // staging visible

        // ---- S = Q K^T for this wave's 16-row stripe ----
        f32x4 sf[4];
#pragma unroll
        for (int nt = 0; nt < 4; ++nt) {
            f32x4 a2 = (f32x4){0.f, 0.f, 0.f, 0.f};
#pragma unroll
            for (int kc = 0; kc < 2; ++kc) {
                bf16x8 bk = *(const bf16x8*)&sK[(nt * 2 + kc) * 512 + lane * 8];
                a2 = __builtin_amdgcn_mfma_f32_16x16x32_bf16(aq[kc], bk, a2, 0, 0, 0);
            }
            sf[nt] = a2;
        }

        // ---- scale + causal mask (diagonal tile only) ----
        const bool diag = (j0 == qi0);
#pragma unroll
        for (int nt = 0; nt < 4; ++nt)
#pragma unroll
            for (int r = 0; r < 4; ++r) {
                float x = sf[nt][r] * 0.125f;    // 1/sqrt(DK)
                if (diag) {
                    int qrow = w * 16 + qg * 4 + r;
                    int col  = nt * 16 + ln;
                    if (col > qrow) x = -3.0e38f;
                }
                sf[nt][r] = x;
            }

        // ---- online softmax (row stats across the 16 lanes sharing qg) ----
        float rmax[4];
#pragma unroll
        for (int r = 0; r < 4; ++r)
            rmax[r] = fmaxf(fmaxf(sf[0][r], sf[1][r]), fmaxf(sf[2][r], sf[3][r]));
#pragma unroll
        for (int off = 8; off >= 1; off >>= 1)
#pragma unroll
            for (int r = 0; r < 4; ++r)
                rmax[r] = fmaxf(rmax[r], __shfl_xor(rmax[r], off));

        float alpha[4];
#pragma unroll
        for (int r = 0; r < 4; ++r) {
            float mn = fmaxf(m_r[r], rmax[r]);
            alpha[r] = __expf(m_r[r] - mn);
            m_r[r] = mn;
        }

        float pf[4][4];
        float rsum[4] = {0.f, 0.f, 0.f, 0.f};
#pragma unroll
        for (int nt = 0; nt < 4; ++nt)
#pragma unroll
            for (int r = 0; r < 4; ++r) {
                float p = __expf(sf[nt][r] - m_r[r]);
                pf[nt][r] = p;
                rsum[r] += p;
            }
#pragma unroll
        for (int off = 8; off >= 1; off >>= 1)
#pragma unroll
            for (int r = 0; r < 4; ++r)
                rsum[r] += __shfl_xor(rsum[r], off);
#pragma unroll
        for (int r = 0; r < 4; ++r) l_r[r] = l_r[r] * alpha[r] + rsum[r];
#pragma unroll
        for (int nt = 0; nt < 4; ++nt)
#pragma unroll
            for (int r = 0; r < 4; ++r) ofrag[nt][r] *= alpha[r];

        // ---- P: C-layout regs -> swizzled LDS -> A-layout frags ----
        // (wave-private rows; compiler's lgkmcnt ordering covers the RAW dep)
#pragma unroll
        for (int nt = 0; nt < 4; ++nt)
#pragma unroll
            for (int r = 0; r < 4; ++r) {
                int row = w * 16 + qg * 4 + r;
                int col = (nt * 16 + ln) ^ (((w * 4 + qg) & 7) * 8);
                sP[row * PSTR + col] = f2bf(pf[nt][r]);
            }

        bf16x8 apf[2];
#pragma unroll
        for (int kc = 0; kc < 2; ++kc) {
            int row = w * 16 + ln;
            int col = (kc * 32 + qg * 8) ^ ((((row >> 2) & 7)) * 8);
            apf[kc] = *(const bf16x8*)&sP[row * PSTR + col];
        }

        // ---- O += P V ----
#pragma unroll
        for (int nt = 0; nt < 4; ++nt) {
#pragma unroll
            for (int kc = 0; kc < 2; ++kc) {
                int dk = nt * 16 + ln;
                int ci = (dk >> 3) & 7;
                bf16x8 bv = *(const bf16x8*)&sVt[dk * 64 + ((kc * 32 + qg * 8) ^ (ci * 8))];
                ofrag[nt] = __builtin_amdgcn_mfma_f32_16x16x32_bf16(apf[kc], bv, ofrag[nt], 0, 0, 0);
            }
        }
    }

    // ---- epilogue: normalize, write bf16 ctx in [B,S,D] layout ----
#pragma unroll
    for (int nt = 0; nt < 4; ++nt)
#pragma unroll
        for (int r = 0; r < 4; ++r) {
            int gq = qi0 + w * 16 + qg * 4 + r;
            O[(rowbase + gq) * DMODEL + colbase + nt * 16 + ln] =
                f2bf(ofrag[nt][r] / l_r[r]);
        }
}

// ---------------------------------------------------------------------------
extern "C" void kernel_launch(void* const* d_in, const int* in_sizes, int n_in,
                              void* d_out, int out_size, void* d_ws, size_t ws_size,
                              hipStream_t stream)
{
    const float* q  = (const float*)d_in[0];
    const float* k  = (const float*)d_in[1];
    const float* v  = (const float*)d_in[2];
    // d_in[3] = mask (int32 tril) — causality applied analytically (j<=i).
    const float* wq = (const float*)d_in[4];
    const float* bq = (const float*)d_in[5];
    const float* wk = (const float*)d_in[6];
    const float* bk = (const float*)d_in[7];
    const float* wv = (const float*)d_in[8];
    const float* bv = (const float*)d_in[9];
    const float* wo = (const float*)d_in[10];
    const float* bo = (const float*)d_in[11];
    float* out = (float*)d_out;

    const size_t mat  = (size_t)MTOK * DMODEL;     // 4M elements
    const size_t wmat = (size_t)DMODEL * DMODEL;   // 1M elements
    unsigned short* Abq = (unsigned short*)d_ws;   // bf16 activations
    unsigned short* Abk = Abq + mat;
    unsigned short* Abv = Abk + mat;
    unsigned short* WtQ = Abv + mat;               // bf16 transposed weights
    unsigned short* WtK = WtQ + wmat;
    unsigned short* WtV = WtK + wmat;
    unsigned short* WtO = WtV + wmat;
    unsigned short* Qb  = WtO + wmat;              // bf16 projections
    unsigned short* Kb  = Qb + mat;
    unsigned short* Vb  = Kb + mat;
    unsigned short* CTX = Vb + mat;                // bf16 attention output

    cvt3_bf16_kernel<<<dim3((unsigned)(mat / 2048), 1, 3), 256, 0, stream>>>(
        q, k, v, Abq, Abk, Abv, (int)mat);
    wtrans_kernel<<<dim3(32, 32, 4), 256, 0, stream>>>(wq, wk, wv, wo, WtQ, WtK, WtV, WtO);

    // fused Q/K/V projections: tile 128x128, grid (8,32,3) = 768 blocks (3/CU)
    Gemm3 gqkv;
    gqkv.A[0] = Abq; gqkv.A[1] = Abk; gqkv.A[2] = Abv;
    gqkv.Bt[0] = WtQ; gqkv.Bt[1] = WtK; gqkv.Bt[2] = WtV;
    gqkv.bias[0] = bq; gqkv.bias[1] = bk; gqkv.bias[2] = bv;
    gqkv.C[0] = Qb; gqkv.C[1] = Kb; gqkv.C[2] = Vb;
    gemm_direct_kernel<unsigned short, 4><<<dim3(DMODEL / 128, MTOK / 128, 3), 256, 0, stream>>>(
        gqkv, MTOK, DMODEL, DMODEL);

    attn_mfma_kernel<<<BATCH * NHEAD * (SEQ / BR), 256, 0, stream>>>(Qb, Kb, Vb, CTX);

    // output projection: tile 128x64, grid (16,32) = 512 blocks (2/CU)
    Gemm3 go;
    go.A[0] = CTX; go.Bt[0] = WtO; go.bias[0] = bo; go.C[0] = out;
    go.A[1] = go.A[2] = nullptr; go.Bt[1] = go.Bt[2] = nullptr;
    go.bias[1] = go.bias[2] = nullptr; go.C[1] = go.C[2] = nullptr;
    gemm_direct_kernel<float, 2><<<dim3(DMODEL / 64, MTOK / 128, 1), 256, 0, stream>>>(
        go, MTOK, DMODEL, DMODEL);
}

// Round 5
// 310.838 us; speedup vs baseline: 1.1624x; 1.1624x over previous
//
#include <hip/hip_runtime.h>
#include <hip/hip_bf16.h>

// Problem constants (from reference)
#define BATCH 2
#define SEQ   2048
#define DMODEL 1024
#define NHEAD 16
#define DK    64
#define MTOK  (BATCH * SEQ)      // 4096 rows for the projection GEMMs

typedef __attribute__((ext_vector_type(8))) short bf16x8;   // 8 bf16 in 4 VGPRs
typedef __attribute__((ext_vector_type(4))) float f32x4;    // MFMA 16x16 accumulator

// float -> bf16 bits, round-to-nearest-even
__device__ __forceinline__ unsigned short f2bf(float x) {
    unsigned u = __float_as_uint(x);
    u = (u + 0x7FFFu + ((u >> 16) & 1u)) >> 16;
    return (unsigned short)u;
}

__device__ __forceinline__ void store_out(float* p, float v)          { *p = v; }
__device__ __forceinline__ void store_out(unsigned short* p, float v) { *p = f2bf(v); }

// async global->LDS, 16 B per lane; LDS dest = wave-uniform base + lane*16.
// Per-lane SOURCE addresses are arbitrary (gather) — verified rounds 2-4.
__device__ __forceinline__ void g2lds16(const void* g, void* l) {
    __builtin_amdgcn_global_load_lds(
        (const __attribute__((address_space(1))) void*)g,
        (__attribute__((address_space(3))) void*)l, 16, 0, 0);
}

// ---------------------------------------------------------------------------
// fp32 -> bf16 elementwise convert, 3 tensors in one launch (z selects).
// ---------------------------------------------------------------------------
__global__ __launch_bounds__(256) void cvt3_bf16_kernel(
    const float* __restrict__ s0, const float* __restrict__ s1,
    const float* __restrict__ s2,
    unsigned short* __restrict__ d0, unsigned short* __restrict__ d1,
    unsigned short* __restrict__ d2, int n)
{
    const float* src; unsigned short* dst;
    switch (blockIdx.z) {
        case 0:  src = s0; dst = d0; break;
        case 1:  src = s1; dst = d1; break;
        default: src = s2; dst = d2; break;
    }
    int i = (blockIdx.x * 256 + threadIdx.x) * 8;
    if (i >= n) return;
    float4 a = *(const float4*)(src + i);
    float4 b = *(const float4*)(src + i + 4);
    union { unsigned short s[8]; uint4 u; } o;
    o.s[0] = f2bf(a.x); o.s[1] = f2bf(a.y); o.s[2] = f2bf(a.z); o.s[3] = f2bf(a.w);
    o.s[4] = f2bf(b.x); o.s[5] = f2bf(b.y); o.s[6] = f2bf(b.z); o.s[7] = f2bf(b.w);
    *(uint4*)(dst + i) = o.u;
}

// ---------------------------------------------------------------------------
// Transpose + convert the 4 weight matrices: Wt[n][k] = (bf16)W[k][n], 1024^2.
// ---------------------------------------------------------------------------
__global__ __launch_bounds__(256) void wtrans_kernel(
    const float* __restrict__ w0, const float* __restrict__ w1,
    const float* __restrict__ w2, const float* __restrict__ w3,
    unsigned short* __restrict__ t0, unsigned short* __restrict__ t1,
    unsigned short* __restrict__ t2, unsigned short* __restrict__ t3)
{
    __shared__ float tile[32][33];
    const float* W; unsigned short* T;
    switch (blockIdx.z) {
        case 0:  W = w0; T = t0; break;
        case 1:  W = w1; T = t1; break;
        case 2:  W = w2; T = t2; break;
        default: W = w3; T = t3; break;
    }
    const int n0 = blockIdx.x * 32, k0 = blockIdx.y * 32;
    const int t  = threadIdx.x;
    const int r  = t >> 3;          // 0..31
    const int c4 = (t & 7) * 4;     // 0..28

    float4 v = *(const float4*)&W[(size_t)(k0 + r) * DMODEL + n0 + c4];
    tile[r][c4 + 0] = v.x; tile[r][c4 + 1] = v.y;
    tile[r][c4 + 2] = v.z; tile[r][c4 + 3] = v.w;
    __syncthreads();

    union { unsigned short s[4]; uint2 u; } o;
#pragma unroll
    for (int u = 0; u < 4; ++u) o.s[u] = f2bf(tile[c4 + u][r]);
    *(uint2*)&T[(size_t)(n0 + r) * DMODEL + k0 + c4] = o.u;
}

// ---------------------------------------------------------------------------
// m97-recipe MFMA GEMM: C[M,N] = A[M,K] @ Bt[N,K]^T + bias (fp32 acc).
// Tile 128x128, BK=64, 256 threads = 4 waves (wm=w>>1 row-half, wn=w&1
// col-half, each wave 64x64 out = 4x4 16x16 frags, acc 64 VGPR).
// LDS is FRAGMENT-ORDERED: each 1-KB block holds one wave-fragment's
// 64 lanes x 16 B contiguously -> every ds_read_b128 is a conflict-free
// contiguous wave read; global_load_lds gathers per-lane source elements.
// Per wave per K-iter: 32 MFMA + 16 ds_read_b128 + 8 g2lds16 + 2 barriers
// (the verified m97 ratio, 874 TF @ 3 blocks/CU).
// z-fused: blockIdx.z selects one of up to 3 independent GEMMs.
// ---------------------------------------------------------------------------
struct Gemm3 {
    const unsigned short* A[3];
    const unsigned short* Bt[3];
    const float* bias[3];
    void* C[3];
};

template <typename OutT>
__global__ __launch_bounds__(256) void gemm_lds_kernel(Gemm3 g, int M, int N, int K)
{
    __shared__ unsigned short sA[16 * 512];   // 16 KB
    __shared__ unsigned short sB[16 * 512];   // 16 KB

    const int z = blockIdx.z;
    const unsigned short* __restrict__ A  = g.A[z];
    const unsigned short* __restrict__ Bt = g.Bt[z];
    const float* __restrict__ bias = g.bias[z];
    OutT* __restrict__ C = (OutT*)g.C[z];

    const int t    = threadIdx.x;
    const int w    = t >> 6;
    const int lane = t & 63;
    const int ln   = lane & 15;
    const int qg   = lane >> 4;
    const int wm   = w >> 1;
    const int wn   = w & 1;
    const int row0 = blockIdx.y * 128;
    const int col0 = blockIdx.x * 128;

    // Precompute this wave's 8 staging (src, lds) pairs.
    // Block s in [0,16): A, mtg=s>>1, kc=s&1.  s in [16,32): B, same split.
    const unsigned short* sp[8];
    unsigned short* lp[8];
#pragma unroll
    for (int i = 0; i < 8; ++i) {
        const int s = w * 8 + i;                 // wave-uniform
        if (s < 16) {
            const int mtg = s >> 1, kc = s & 1;
            sp[i] = A + (size_t)(row0 + mtg * 16 + ln) * K + kc * 32 + qg * 8;
            lp[i] = &sA[s * 512];
        } else {
            const int bi = s - 16;
            const int ntg = bi >> 1, kc = bi & 1;
            sp[i] = Bt + (size_t)(col0 + ntg * 16 + ln) * K + kc * 32 + qg * 8;
            lp[i] = &sB[bi * 512];
        }
    }

    f32x4 acc[4][4];
#pragma unroll
    for (int mt = 0; mt < 4; ++mt)
#pragma unroll
        for (int nt = 0; nt < 4; ++nt) acc[mt][nt] = (f32x4){0.f, 0.f, 0.f, 0.f};

    for (int kt = 0; kt < K / 64; ++kt) {
        __syncthreads();                         // prev iter's LDS reads done
        const int koff = kt * 64;
#pragma unroll
        for (int i = 0; i < 8; ++i)
            g2lds16(sp[i] + koff, lp[i]);
        __syncthreads();                         // staging visible (vmcnt drain)

#pragma unroll
        for (int kc = 0; kc < 2; ++kc) {
            bf16x8 aF[4], bF[4];
#pragma unroll
            for (int mt = 0; mt < 4; ++mt)
                aF[mt] = *(const bf16x8*)&sA[(((wm * 4 + mt) * 2) + kc) * 512 + lane * 8];
#pragma unroll
            for (int nt = 0; nt < 4; ++nt)
                bF[nt] = *(const bf16x8*)&sB[(((wn * 4 + nt) * 2) + kc) * 512 + lane * 8];
#pragma unroll
            for (int mt = 0; mt < 4; ++mt)
#pragma unroll
                for (int nt = 0; nt < 4; ++nt)
                    acc[mt][nt] = __builtin_amdgcn_mfma_f32_16x16x32_bf16(
                        aF[mt], bF[nt], acc[mt][nt], 0, 0, 0);
        }
    }

    float bfv[4];
#pragma unroll
    for (int nt = 0; nt < 4; ++nt)
        bfv[nt] = bias[col0 + wn * 64 + nt * 16 + ln];

    // epilogue: C/D layout col=ln, row=qg*4+r
#pragma unroll
    for (int mt = 0; mt < 4; ++mt)
#pragma unroll
        for (int nt = 0; nt < 4; ++nt)
#pragma unroll
            for (int r = 0; r < 4; ++r) {
                int row = row0 + wm * 64 + mt * 16 + qg * 4 + r;
                int col = col0 + wn * 64 + nt * 16 + ln;
                store_out(&C[(size_t)row * N + col], acc[mt][nt][r] + bfv[nt]);
            }
}

// ---------------------------------------------------------------------------
// Flash attention with MFMA (unchanged from round 4):
//  - Q, K: fragment-ordered global_load_lds gather (conflict-free, no VALU)
//  - V: in-LDS transpose with XOR swizzle addr = dk*64 + (j ^ 8*((dk>>3)&7))
//  - sP: row-major stride 72 with col ^ 8*((row>>2)&7) swizzle
// ---------------------------------------------------------------------------
#define BR 64
#define BC 64
#define PSTR 72

__global__ __launch_bounds__(256, 4) void attn_mfma_kernel(
    const unsigned short* __restrict__ Qg, const unsigned short* __restrict__ Kg,
    const unsigned short* __restrict__ Vg, unsigned short* __restrict__ O)
{
    __shared__ unsigned short sQ[8 * 512];
    __shared__ unsigned short sK[8 * 512];
    __shared__ unsigned short sVt[DK * 64];
    __shared__ unsigned short sP[BR * PSTR];

    const int t    = threadIdx.x;
    const int w    = t >> 6;
    const int lane = t & 63;
    const int ln   = lane & 15;
    const int qg   = lane >> 4;

    const int id  = blockIdx.x;
    const int bh  = id & 31;
    const int qt  = (SEQ / BR - 1) - (id >> 5);   // heavy tiles first
    const int b   = bh >> 4;
    const int h   = bh & 15;
    const int qi0 = qt * BR;

    const size_t rowbase = (size_t)b * SEQ;
    const size_t colbase = (size_t)h * DK;

#pragma unroll
    for (int i = 0; i < 2; ++i) {
        const int s = w * 2 + i;
        const unsigned short* gp =
            Qg + (rowbase + qi0 + w * 16 + ln) * DMODEL + colbase + i * 32 + qg * 8;
        g2lds16(gp, &sQ[s * 512]);
    }
    __syncthreads();

    bf16x8 aq[2];
#pragma unroll
    for (int kc = 0; kc < 2; ++kc)
        aq[kc] = *(const bf16x8*)&sQ[(w * 2 + kc) * 512 + lane * 8];

    f32x4 ofrag[4];
#pragma unroll
    for (int nt = 0; nt < 4; ++nt) ofrag[nt] = (f32x4){0.f, 0.f, 0.f, 0.f};
    float m_r[4], l_r[4];
#pragma unroll
    for (int r = 0; r < 4; ++r) { m_r[r] = -3.0e38f; l_r[r] = 0.f; }

    for (int j0 = 0; j0 <= qi0; j0 += BC) {
        __syncthreads();

#pragma unroll
        for (int i = 0; i < 2; ++i) {
            const int s  = w * 2 + i;
            const int nt = s >> 1, kc = s & 1;
            const unsigned short* gp =
                Kg + (rowbase + j0 + nt * 16 + ln) * DMODEL + colbase + kc * 32 + qg * 8;
            g2lds16(gp, &sK[s * 512]);
        }
#pragma unroll
        for (int it = 0; it < 2; ++it) {
            int chunk = t + 256 * it;
            int r  = chunk >> 3;
            int c  = (chunk & 7) * 8;
            int ci = chunk & 7;
            union { uint4 u; unsigned short s[8]; } d;
            d.u = *(const uint4*)&Vg[(rowbase + j0 + r) * DMODEL + colbase + c];
#pragma unroll
            for (int u = 0; u < 8; ++u)
                sVt[(c + u) * 64 + (r ^ (ci * 8))] = d.s[u];
        }
        __syncthreads();

        f32x4 sf[4];
#pragma unroll
        for (int nt = 0; nt < 4; ++nt) {
            f32x4 a2 = (f32x4){0.f, 0.f, 0.f, 0.f};
#pragma unroll
            for (int kc = 0; kc < 2; ++kc) {
                bf16x8 bk = *(const bf16x8*)&sK[(nt * 2 + kc) * 512 + lane * 8];
                a2 = __builtin_amdgcn_mfma_f32_16x16x32_bf16(aq[kc], bk, a2, 0, 0, 0);
            }
            sf[nt] = a2;
        }

        const bool diag = (j0 == qi0);
#pragma unroll
        for (int nt = 0; nt < 4; ++nt)
#pragma unroll
            for (int r = 0; r < 4; ++r) {
                float x = sf[nt][r] * 0.125f;
                if (diag) {
                    int qrow = w * 16 + qg * 4 + r;
                    int col  = nt * 16 + ln;
                    if (col > qrow) x = -3.0e38f;
                }
                sf[nt][r] = x;
            }

        float rmax[4];
#pragma unroll
        for (int r = 0; r < 4; ++r)
            rmax[r] = fmaxf(fmaxf(sf[0][r], sf[1][r]), fmaxf(sf[2][r], sf[3][r]));
#pragma unroll
        for (int off = 8; off >= 1; off >>= 1)
#pragma unroll
            for (int r = 0; r < 4; ++r)
                rmax[r] = fmaxf(rmax[r], __shfl_xor(rmax[r], off));

        float alpha[4];
#pragma unroll
        for (int r = 0; r < 4; ++r) {
            float mn = fmaxf(m_r[r], rmax[r]);
            alpha[r] = __expf(m_r[r] - mn);
            m_r[r] = mn;
        }

        float pf[4][4];
        float rsum[4] = {0.f, 0.f, 0.f, 0.f};
#pragma unroll
        for (int nt = 0; nt < 4; ++nt)
#pragma unroll
            for (int r = 0; r < 4; ++r) {
                float p = __expf(sf[nt][r] - m_r[r]);
                pf[nt][r] = p;
                rsum[r] += p;
            }
#pragma unroll
        for (int off = 8; off >= 1; off >>= 1)
#pragma unroll
            for (int r = 0; r < 4; ++r)
                rsum[r] += __shfl_xor(rsum[r], off);
#pragma unroll
        for (int r = 0; r < 4; ++r) l_r[r] = l_r[r] * alpha[r] + rsum[r];
#pragma unroll
        for (int nt = 0; nt < 4; ++nt)
#pragma unroll
            for (int r = 0; r < 4; ++r) ofrag[nt][r] *= alpha[r];

#pragma unroll
        for (int nt = 0; nt < 4; ++nt)
#pragma unroll
            for (int r = 0; r < 4; ++r) {
                int row = w * 16 + qg * 4 + r;
                int col = (nt * 16 + ln) ^ (((w * 4 + qg) & 7) * 8);
                sP[row * PSTR + col] = f2bf(pf[nt][r]);
            }

        bf16x8 apf[2];
#pragma unroll
        for (int kc = 0; kc < 2; ++kc) {
            int row = w * 16 + ln;
            int col = (kc * 32 + qg * 8) ^ ((((row >> 2) & 7)) * 8);
            apf[kc] = *(const bf16x8*)&sP[row * PSTR + col];
        }

#pragma unroll
        for (int nt = 0; nt < 4; ++nt) {
#pragma unroll
            for (int kc = 0; kc < 2; ++kc) {
                int dk = nt * 16 + ln;
                int ci = (dk >> 3) & 7;
                bf16x8 bv = *(const bf16x8*)&sVt[dk * 64 + ((kc * 32 + qg * 8) ^ (ci * 8))];
                ofrag[nt] = __builtin_amdgcn_mfma_f32_16x16x32_bf16(apf[kc], bv, ofrag[nt], 0, 0, 0);
            }
        }
    }

#pragma unroll
    for (int nt = 0; nt < 4; ++nt)
#pragma unroll
        for (int r = 0; r < 4; ++r) {
            int gq = qi0 + w * 16 + qg * 4 + r;
            O[(rowbase + gq) * DMODEL + colbase + nt * 16 + ln] =
                f2bf(ofrag[nt][r] / l_r[r]);
        }
}

// ---------------------------------------------------------------------------
extern "C" void kernel_launch(void* const* d_in, const int* in_sizes, int n_in,
                              void* d_out, int out_size, void* d_ws, size_t ws_size,
                              hipStream_t stream)
{
    const float* q  = (const float*)d_in[0];
    const float* k  = (const float*)d_in[1];
    const float* v  = (const float*)d_in[2];
    // d_in[3] = mask (int32 tril) — causality applied analytically (j<=i).
    const float* wq = (const float*)d_in[4];
    const float* bq = (const float*)d_in[5];
    const float* wk = (const float*)d_in[6];
    const float* bk = (const float*)d_in[7];
    const float* wv = (const float*)d_in[8];
    const float* bv = (const float*)d_in[9];
    const float* wo = (const float*)d_in[10];
    const float* bo = (const float*)d_in[11];
    float* out = (float*)d_out;

    const size_t mat  = (size_t)MTOK * DMODEL;     // 4M elements
    const size_t wmat = (size_t)DMODEL * DMODEL;   // 1M elements
    unsigned short* Abq = (unsigned short*)d_ws;   // bf16 activations
    unsigned short* Abk = Abq + mat;
    unsigned short* Abv = Abk + mat;
    unsigned short* WtQ = Abv + mat;               // bf16 transposed weights
    unsigned short* WtK = WtQ + wmat;
    unsigned short* WtV = WtK + wmat;
    unsigned short* WtO = WtV + wmat;
    unsigned short* Qb  = WtO + wmat;              // bf16 projections
    unsigned short* Kb  = Qb + mat;
    unsigned short* Vb  = Kb + mat;
    unsigned short* CTX = Vb + mat;                // bf16 attention output

    cvt3_bf16_kernel<<<dim3((unsigned)(mat / 2048), 1, 3), 256, 0, stream>>>(
        q, k, v, Abq, Abk, Abv, (int)mat);
    wtrans_kernel<<<dim3(32, 32, 4), 256, 0, stream>>>(wq, wk, wv, wo, WtQ, WtK, WtV, WtO);

    // fused Q/K/V projections: tile 128x128, grid (8,32,3) = 768 blocks (3/CU)
    Gemm3 gqkv;
    gqkv.A[0] = Abq; gqkv.A[1] = Abk; gqkv.A[2] = Abv;
    gqkv.Bt[0] = WtQ; gqkv.Bt[1] = WtK; gqkv.Bt[2] = WtV;
    gqkv.bias[0] = bq; gqkv.bias[1] = bk; gqkv.bias[2] = bv;
    gqkv.C[0] = Qb; gqkv.C[1] = Kb; gqkv.C[2] = Vb;
    gemm_lds_kernel<unsigned short><<<dim3(DMODEL / 128, MTOK / 128, 3), 256, 0, stream>>>(
        gqkv, MTOK, DMODEL, DMODEL);

    attn_mfma_kernel<<<BATCH * NHEAD * (SEQ / BR), 256, 0, stream>>>(Qb, Kb, Vb, CTX);

    // output projection: same kernel, grid (8,32,1) = 256 blocks
    Gemm3 go;
    go.A[0] = CTX; go.Bt[0] = WtO; go.bias[0] = bo; go.C[0] = out;
    go.A[1] = go.A[2] = nullptr; go.Bt[1] = go.Bt[2] = nullptr;
    go.bias[1] = go.bias[2] = nullptr; go.C[1] = go.C[2] = nullptr;
    gemm_lds_kernel<float><<<dim3(DMODEL / 128, MTOK / 128, 1), 256, 0, stream>>>(
        go, MTOK, DMODEL, DMODEL);
}

// Round 6
// 272.624 us; speedup vs baseline: 1.3254x; 1.1402x over previous
//
#include <hip/hip_runtime.h>
#include <hip/hip_bf16.h>

// Problem constants (from reference)
#define BATCH 2
#define SEQ   2048
#define DMODEL 1024
#define NHEAD 16
#define DK    64
#define MTOK  (BATCH * SEQ)      // 4096 token rows

typedef __attribute__((ext_vector_type(8))) short bf16x8;   // 8 bf16 in 4 VGPRs
typedef __attribute__((ext_vector_type(4))) float f32x4;    // MFMA 16x16 accumulator

// float -> bf16 bits, round-to-nearest-even
__device__ __forceinline__ unsigned short f2bf(float x) {
    unsigned u = __float_as_uint(x);
    u = (u + 0x7FFFu + ((u >> 16) & 1u)) >> 16;
    return (unsigned short)u;
}

__device__ __forceinline__ void store_out(float* p, float v)          { *p = v; }
__device__ __forceinline__ void store_out(unsigned short* p, float v) { *p = f2bf(v); }

// async global->LDS, 16 B per lane; LDS dest = wave-uniform base + lane*16.
// Per-lane SOURCE addresses are arbitrary (gather) — verified rounds 2-5.
__device__ __forceinline__ void g2lds16(const void* g, void* l) {
    __builtin_amdgcn_global_load_lds(
        (const __attribute__((address_space(1))) void*)g,
        (__attribute__((address_space(3))) void*)l, 16, 0, 0);
}

// ---------------------------------------------------------------------------
// fp32 -> bf16 elementwise convert, 3 tensors in one launch (z selects).
// ---------------------------------------------------------------------------
__global__ __launch_bounds__(256) void cvt3_bf16_kernel(
    const float* __restrict__ s0, const float* __restrict__ s1,
    const float* __restrict__ s2,
    unsigned short* __restrict__ d0, unsigned short* __restrict__ d1,
    unsigned short* __restrict__ d2, int n)
{
    const float* src; unsigned short* dst;
    switch (blockIdx.z) {
        case 0:  src = s0; dst = d0; break;
        case 1:  src = s1; dst = d1; break;
        default: src = s2; dst = d2; break;
    }
    int i = (blockIdx.x * 256 + threadIdx.x) * 8;
    if (i >= n) return;
    float4 a = *(const float4*)(src + i);
    float4 b = *(const float4*)(src + i + 4);
    union { unsigned short s[8]; uint4 u; } o;
    o.s[0] = f2bf(a.x); o.s[1] = f2bf(a.y); o.s[2] = f2bf(a.z); o.s[3] = f2bf(a.w);
    o.s[4] = f2bf(b.x); o.s[5] = f2bf(b.y); o.s[6] = f2bf(b.z); o.s[7] = f2bf(b.w);
    *(uint4*)(dst + i) = o.u;
}

// ---------------------------------------------------------------------------
// Transpose + convert the 4 weight matrices: Wt[n][k] = (bf16)W[k][n], 1024^2.
// ---------------------------------------------------------------------------
__global__ __launch_bounds__(256) void wtrans_kernel(
    const float* __restrict__ w0, const float* __restrict__ w1,
    const float* __restrict__ w2, const float* __restrict__ w3,
    unsigned short* __restrict__ t0, unsigned short* __restrict__ t1,
    unsigned short* __restrict__ t2, unsigned short* __restrict__ t3)
{
    __shared__ float tile[32][33];
    const float* W; unsigned short* T;
    switch (blockIdx.z) {
        case 0:  W = w0; T = t0; break;
        case 1:  W = w1; T = t1; break;
        case 2:  W = w2; T = t2; break;
        default: W = w3; T = t3; break;
    }
    const int n0 = blockIdx.x * 32, k0 = blockIdx.y * 32;
    const int t  = threadIdx.x;
    const int r  = t >> 3;          // 0..31
    const int c4 = (t & 7) * 4;     // 0..28

    float4 v = *(const float4*)&W[(size_t)(k0 + r) * DMODEL + n0 + c4];
    tile[r][c4 + 0] = v.x; tile[r][c4 + 1] = v.y;
    tile[r][c4 + 2] = v.z; tile[r][c4 + 3] = v.w;
    __syncthreads();

    union { unsigned short s[4]; uint2 u; } o;
#pragma unroll
    for (int u = 0; u < 4; ++u) o.s[u] = f2bf(tile[c4 + u][r]);
    *(uint2*)&T[(size_t)(n0 + r) * DMODEL + k0 + c4] = o.u;
}

// ---------------------------------------------------------------------------
// m97-recipe MFMA GEMM: C[M,N] = A[M,K] @ Bt[N,K]^T + bias, scaled (fp32 acc).
// Tile 128 x (NTILE*32), BK=64, fragment-ordered LDS + global_load_lds gather.
// Per-z params allow swapped-operand GEMMs (used for the transposed-V
// projection: A=WtV[d][k], Bt=Abv[token][k], C=VT[d][token], bias by ROW).
// ---------------------------------------------------------------------------
struct GemmP {
    const unsigned short* A;
    const unsigned short* Bt;
    const float* bias;
    void* C;
    int N, K, ctShift, biasByRow;
    float scale;
};
struct Gemm3 { GemmP p[3]; };

template <typename OutT, int NTILE>
__global__ __launch_bounds__(256) void gemm_lds_kernel(Gemm3 g)
{
    __shared__ unsigned short sA[16 * 512];          // 16 KB
    __shared__ unsigned short sB[4 * NTILE * 512];   // 8/16 KB

    const GemmP p = g.p[blockIdx.z];
    const unsigned short* __restrict__ A  = p.A;
    const unsigned short* __restrict__ Bt = p.Bt;
    OutT* __restrict__ C = (OutT*)p.C;
    const int K = p.K, N = p.N;

    const int bid = blockIdx.x;
    const int bx = bid & ((1 << p.ctShift) - 1);
    const int by = bid >> p.ctShift;
    const int row0 = by * 128;
    const int col0 = bx * (NTILE * 32);

    const int t    = threadIdx.x;
    const int w    = t >> 6;
    const int lane = t & 63;
    const int ln   = lane & 15;
    const int qg   = lane >> 4;
    const int wm   = w >> 1;
    const int wn   = w & 1;

    // wave-uniform staging assignments: blocks [0,16) = A, [16,16+4*NTILE) = B
    const int PW = 4 + NTILE;                 // blocks per wave
    const unsigned short* sp[PW];
    unsigned short* lp[PW];
#pragma unroll
    for (int i = 0; i < PW; ++i) {
        const int s = w * PW + i;
        if (s < 16) {
            const int mtg = s >> 1, kc = s & 1;
            sp[i] = A + (size_t)(row0 + mtg * 16 + ln) * K + kc * 32 + qg * 8;
            lp[i] = &sA[s * 512];
        } else {
            const int bi = s - 16;
            const int ntg = bi >> 1, kc = bi & 1;
            sp[i] = Bt + (size_t)(col0 + ntg * 16 + ln) * K + kc * 32 + qg * 8;
            lp[i] = &sB[bi * 512];
        }
    }

    f32x4 acc[4][NTILE];
#pragma unroll
    for (int mt = 0; mt < 4; ++mt)
#pragma unroll
        for (int nt = 0; nt < NTILE; ++nt) acc[mt][nt] = (f32x4){0.f, 0.f, 0.f, 0.f};

    for (int kt = 0; kt < K / 64; ++kt) {
        __syncthreads();
        const int koff = kt * 64;
#pragma unroll
        for (int i = 0; i < PW; ++i)
            g2lds16(sp[i] + koff, lp[i]);
        __syncthreads();

#pragma unroll
        for (int kc = 0; kc < 2; ++kc) {
            bf16x8 aF[4], bF[NTILE];
#pragma unroll
            for (int mt = 0; mt < 4; ++mt)
                aF[mt] = *(const bf16x8*)&sA[(((wm * 4 + mt) * 2) + kc) * 512 + lane * 8];
#pragma unroll
            for (int nt = 0; nt < NTILE; ++nt)
                bF[nt] = *(const bf16x8*)&sB[(((wn * NTILE + nt) * 2) + kc) * 512 + lane * 8];
#pragma unroll
            for (int mt = 0; mt < 4; ++mt)
#pragma unroll
                for (int nt = 0; nt < NTILE; ++nt)
                    acc[mt][nt] = __builtin_amdgcn_mfma_f32_16x16x32_bf16(
                        aF[mt], bF[nt], acc[mt][nt], 0, 0, 0);
        }
    }

    float bcol[NTILE], brow[4][4];
    if (!p.biasByRow) {
#pragma unroll
        for (int nt = 0; nt < NTILE; ++nt)
            bcol[nt] = p.bias[col0 + wn * NTILE * 16 + nt * 16 + ln];
    } else {
#pragma unroll
        for (int mt = 0; mt < 4; ++mt)
#pragma unroll
            for (int r = 0; r < 4; ++r)
                brow[mt][r] = p.bias[row0 + wm * 64 + mt * 16 + qg * 4 + r];
    }

#pragma unroll
    for (int mt = 0; mt < 4; ++mt)
#pragma unroll
        for (int nt = 0; nt < NTILE; ++nt)
#pragma unroll
            for (int r = 0; r < 4; ++r) {
                int row = row0 + wm * 64 + mt * 16 + qg * 4 + r;
                int col = col0 + wn * NTILE * 16 + nt * 16 + ln;
                float bb = p.biasByRow ? brow[mt][r] : bcol[nt];
                store_out(&C[(size_t)row * N + col], (acc[mt][nt][r] + bb) * p.scale);
            }
}

// ---------------------------------------------------------------------------
// Flash attention, round-6 structure:
//  - Q, K, V all staged fragment-ordered via global_load_lds (V comes from the
//    transposed projection VT[d][token] -> contiguous 16B per lane, no LDS
//    transpose, no scalar writes)
//  - double-buffered K/V: prefetch tile j+1 before computing tile j; ONE
//    barrier per tile, with the vmcnt drain overlapped by a full tile of work
//  - l (softmax denom) via MFMA row-sum against an all-ones B fragment
//  - scores arrive pre-scaled by 0.125*log2e (folded into Q projection) ->
//    softmax runs in exp2 domain with zero scale multiplies
// ---------------------------------------------------------------------------
#define BR 64
#define BC 64
#define PSTR 72

__global__ __launch_bounds__(256) void attn_mfma_kernel(
    const unsigned short* __restrict__ Qg, const unsigned short* __restrict__ Kg,
    const unsigned short* __restrict__ VT, unsigned short* __restrict__ O)
{
    __shared__ unsigned short sK[2][8 * 512];   // 16 KB
    __shared__ unsigned short sV[2][8 * 512];   // 16 KB
    __shared__ unsigned short sQ[8 * 512];      // 8 KB
    __shared__ unsigned short sP[BR * PSTR];    // 9 KB

    const int t    = threadIdx.x;
    const int w    = t >> 6;
    const int lane = t & 63;
    const int ln   = lane & 15;
    const int qg   = lane >> 4;

    const int id  = blockIdx.x;
    const int bh  = id & 31;
    const int qt  = (SEQ / BR - 1) - (id >> 5);   // heavy tiles first
    const int b   = bh >> 4;
    const int h   = bh & 15;
    const int qi0 = qt * BR;

    const size_t rowbase = (size_t)b * SEQ;
    const size_t colbase = (size_t)h * DK;

    // ---- stage Q + K/V tile 0 (buf 0) ----
#pragma unroll
    for (int i = 0; i < 2; ++i) {
        const int s = w * 2 + i;
        const int nt = s >> 1, kc = s & 1;
        g2lds16(Qg + (rowbase + qi0 + w * 16 + ln) * DMODEL + colbase + i * 32 + qg * 8,
                &sQ[s * 512]);
        g2lds16(Kg + (rowbase + nt * 16 + ln) * DMODEL + colbase + kc * 32 + qg * 8,
                &sK[0][s * 512]);
        g2lds16(VT + (size_t)(colbase + nt * 16 + ln) * MTOK + rowbase + kc * 32 + qg * 8,
                &sV[0][s * 512]);
    }
    __syncthreads();

    bf16x8 aq[2];
#pragma unroll
    for (int kc = 0; kc < 2; ++kc)
        aq[kc] = *(const bf16x8*)&sQ[(w * 2 + kc) * 512 + lane * 8];

    const short one_bf = (short)0x3F80;
    const bf16x8 bone = (bf16x8){one_bf, one_bf, one_bf, one_bf,
                                 one_bf, one_bf, one_bf, one_bf};

    f32x4 ofrag[4];
#pragma unroll
    for (int nt = 0; nt < 4; ++nt) ofrag[nt] = (f32x4){0.f, 0.f, 0.f, 0.f};
    f32x4 osum = (f32x4){0.f, 0.f, 0.f, 0.f};
    float m_r[4];
#pragma unroll
    for (int r = 0; r < 4; ++r) m_r[r] = -3.0e38f;

    const int ntiles = qt + 1;
    for (int jt = 0; jt < ntiles; ++jt) {
        const int cur = jt & 1;

        // ---- prefetch tile jt+1 into the alternate buffer (latency hidden
        //      behind this tile's compute; drained at the end barrier) ----
        if (jt + 1 < ntiles) {
            const int j1 = (jt + 1) * BC;
            const int nb = cur ^ 1;
#pragma unroll
            for (int i = 0; i < 2; ++i) {
                const int s = w * 2 + i;
                const int nt = s >> 1, kc = s & 1;
                g2lds16(Kg + (rowbase + j1 + nt * 16 + ln) * DMODEL + colbase + kc * 32 + qg * 8,
                        &sK[nb][s * 512]);
                g2lds16(VT + (size_t)(colbase + nt * 16 + ln) * MTOK + rowbase + j1 + kc * 32 + qg * 8,
                        &sV[nb][s * 512]);
            }
        }

        // ---- S = Q K^T (scores pre-scaled by 0.125*log2e) ----
        f32x4 sf[4];
#pragma unroll
        for (int nt = 0; nt < 4; ++nt) {
            f32x4 a2 = (f32x4){0.f, 0.f, 0.f, 0.f};
#pragma unroll
            for (int kc = 0; kc < 2; ++kc) {
                bf16x8 bk = *(const bf16x8*)&sK[cur][(nt * 2 + kc) * 512 + lane * 8];
                a2 = __builtin_amdgcn_mfma_f32_16x16x32_bf16(aq[kc], bk, a2, 0, 0, 0);
            }
            sf[nt] = a2;
        }

        // ---- causal mask (diagonal tile only) ----
        if (jt == ntiles - 1) {
#pragma unroll
            for (int nt = 0; nt < 4; ++nt)
#pragma unroll
                for (int r = 0; r < 4; ++r) {
                    int qrow = w * 16 + qg * 4 + r;
                    int col  = nt * 16 + ln;
                    if (col > qrow) sf[nt][r] = -1.0e30f;
                }
        }

        // ---- online softmax (exp2 domain); l via MFMA row-sum below ----
        float rmax[4];
#pragma unroll
        for (int r = 0; r < 4; ++r)
            rmax[r] = fmaxf(fmaxf(sf[0][r], sf[1][r]), fmaxf(sf[2][r], sf[3][r]));
#pragma unroll
        for (int off = 8; off >= 1; off >>= 1)
#pragma unroll
            for (int r = 0; r < 4; ++r)
                rmax[r] = fmaxf(rmax[r], __shfl_xor(rmax[r], off));

        float alpha[4];
#pragma unroll
        for (int r = 0; r < 4; ++r) {
            float mn = fmaxf(m_r[r], rmax[r]);
            alpha[r] = exp2f(m_r[r] - mn);
            m_r[r] = mn;
        }

#pragma unroll
        for (int nt = 0; nt < 4; ++nt)
#pragma unroll
            for (int r = 0; r < 4; ++r) {
                float pv = exp2f(sf[nt][r] - m_r[r]);
                int row = w * 16 + qg * 4 + r;
                int col = (nt * 16 + ln) ^ (((w * 4 + qg) & 7) * 8);
                sP[row * PSTR + col] = f2bf(pv);
            }

#pragma unroll
        for (int nt = 0; nt < 4; ++nt)
#pragma unroll
            for (int r = 0; r < 4; ++r) ofrag[nt][r] *= alpha[r];
#pragma unroll
        for (int r = 0; r < 4; ++r) osum[r] *= alpha[r];

        // ---- P back as A-fragments ----
        bf16x8 apf[2];
#pragma unroll
        for (int kc = 0; kc < 2; ++kc) {
            int row = w * 16 + ln;
            int col = (kc * 32 + qg * 8) ^ ((((row >> 2) & 7)) * 8);
            apf[kc] = *(const bf16x8*)&sP[row * PSTR + col];
        }

        // ---- O += P V ; l += P . ones (MFMA row-sum) ----
#pragma unroll
        for (int kc = 0; kc < 2; ++kc)
            osum = __builtin_amdgcn_mfma_f32_16x16x32_bf16(apf[kc], bone, osum, 0, 0, 0);
#pragma unroll
        for (int nt = 0; nt < 4; ++nt) {
#pragma unroll
            for (int kc = 0; kc < 2; ++kc) {
                bf16x8 bv = *(const bf16x8*)&sV[cur][(nt * 2 + kc) * 512 + lane * 8];
                ofrag[nt] = __builtin_amdgcn_mfma_f32_16x16x32_bf16(apf[kc], bv, ofrag[nt], 0, 0, 0);
            }
        }

        __syncthreads();    // publish prefetched tile; protect cur for overwrite
    }

    // ---- epilogue: normalize, write bf16 ctx in [B,S,D] layout ----
    float inv[4];
#pragma unroll
    for (int r = 0; r < 4; ++r) inv[r] = 1.0f / osum[r];
#pragma unroll
    for (int nt = 0; nt < 4; ++nt)
#pragma unroll
        for (int r = 0; r < 4; ++r) {
            int gq = qi0 + w * 16 + qg * 4 + r;
            O[(rowbase + gq) * DMODEL + colbase + nt * 16 + ln] =
                f2bf(ofrag[nt][r] * inv[r]);
        }
}

// ---------------------------------------------------------------------------
extern "C" void kernel_launch(void* const* d_in, const int* in_sizes, int n_in,
                              void* d_out, int out_size, void* d_ws, size_t ws_size,
                              hipStream_t stream)
{
    const float* q  = (const float*)d_in[0];
    const float* k  = (const float*)d_in[1];
    const float* v  = (const float*)d_in[2];
    // d_in[3] = mask (int32 tril) — causality applied analytically (j<=i).
    const float* wq = (const float*)d_in[4];
    const float* bq = (const float*)d_in[5];
    const float* wk = (const float*)d_in[6];
    const float* bk = (const float*)d_in[7];
    const float* wv = (const float*)d_in[8];
    const float* bv = (const float*)d_in[9];
    const float* wo = (const float*)d_in[10];
    const float* bo = (const float*)d_in[11];
    float* out = (float*)d_out;

    const size_t mat  = (size_t)MTOK * DMODEL;     // 4M elements
    const size_t wmat = (size_t)DMODEL * DMODEL;   // 1M elements
    unsigned short* Abq = (unsigned short*)d_ws;   // bf16 activations
    unsigned short* Abk = Abq + mat;
    unsigned short* Abv = Abk + mat;
    unsigned short* WtQ = Abv + mat;               // bf16 transposed weights
    unsigned short* WtK = WtQ + wmat;
    unsigned short* WtV = WtK + wmat;
    unsigned short* WtO = WtV + wmat;
    unsigned short* Qb  = WtO + wmat;              // bf16 Q proj (pre-scaled)
    unsigned short* Kb  = Qb + mat;                // bf16 K proj
    unsigned short* VT  = Kb + mat;                // bf16 V proj, TRANSPOSED [D][MTOK]
    unsigned short* CTX = VT + mat;                // bf16 attention output

    cvt3_bf16_kernel<<<dim3((unsigned)(mat / 2048), 1, 3), 256, 0, stream>>>(
        q, k, v, Abq, Abk, Abv, (int)mat);
    wtrans_kernel<<<dim3(32, 32, 4), 256, 0, stream>>>(wq, wk, wv, wo, WtQ, WtK, WtV, WtO);

    // fused projections: z0=Q (pre-scaled by 0.125*log2e), z1=K, z2=V transposed
    const float qscale = 0.125f * 1.44269504088896f;
    Gemm3 g;
    g.p[0] = (GemmP){Abq, WtQ, bq, (void*)Qb, DMODEL, DMODEL, 3, 0, qscale};
    g.p[1] = (GemmP){Abk, WtK, bk, (void*)Kb, DMODEL, DMODEL, 3, 0, 1.0f};
    g.p[2] = (GemmP){WtV, Abv, bv, (void*)VT, MTOK,   DMODEL, 5, 1, 1.0f};  // swapped operands
    gemm_lds_kernel<unsigned short, 4><<<dim3(256, 1, 3), 256, 0, stream>>>(g);

    attn_mfma_kernel<<<BATCH * NHEAD * (SEQ / BR), 256, 0, stream>>>(Qb, Kb, VT, CTX);

    // output projection: tile 128x64 -> 512 blocks (2/CU)
    Gemm3 go;
    go.p[0] = (GemmP){CTX, WtO, bo, (void*)out, DMODEL, DMODEL, 4, 0, 1.0f};
    go.p[1] = go.p[0];
    go.p[2] = go.p[0];
    gemm_lds_kernel<float, 2><<<dim3(512, 1, 1), 256, 0, stream>>>(go);
}